// Round 5
// baseline (68.886 us; speedup 1.0000x reference)
//
#include <hip/hip_runtime.h>
#include <stdint.h>

#define N_ATOMS 8192
#define KNB 32            // MAX_NEIGHBORS
#define CUTOFF_F 5.0f
#define N_MOLS 64
#define CAP 256           // max supported molecule size (validated R1-R4)

// Kernel 1: molecule ranges by boundary detection on the sorted batch array.
// ranges[2m]=start, ranges[2m+1]=end. Replaces per-wave range discovery with
// 2 scalar loads (R3 measured this worth ~14 us vs binary search; R4 showed
// the inline ballot-scan gave it all back).
__global__ void mol_ranges_kernel(const int* __restrict__ batch, int* __restrict__ ranges) {
    const int k = blockIdx.x * blockDim.x + threadIdx.x;
    if (k >= N_ATOMS) return;
    const int v = batch[k];
    if (k == 0) {
        ranges[0 + 2 * v] = 0;
    } else {
        const int w = batch[k - 1];
        if (w != v) { ranges[2 * w + 1] = k; ranges[2 * v] = k; }
    }
    if (k == N_ATOMS - 1) ranges[2 * v + 1] = N_ATOMS;
}

// Kernel 2: 256-thread blocks, 4 waves/block, each wave owns an atom PAIR
// (8 atoms/block -> 1024 dispatch packets instead of 4096). Pairs share one
// pos[j]/sqj load per candidate. Valid keys (dist_bits<<32 | j) are
// wave-compacted into wave-private LDS; rank (#{strictly smaller}) is the
// output slot — exact jax.lax.top_k order (ascending dist, lower index on
// ties). Epilogue: 64 lanes write 64 contiguous edges, fully coalesced.
__global__ __launch_bounds__(256) void radius_graph_kernel(
    const float* __restrict__ pos, const int* __restrict__ batch,
    const int* __restrict__ ranges, float* __restrict__ out)
{
    const int wave = threadIdx.x >> 6;
    const int lane = threadIdx.x & 63;
    const int i0   = blockIdx.x * 8 + wave * 2;
    const int i1   = i0 + 1;

    __shared__ uint64_t list[4][2][CAP];   // [wave][atom][key]
    __shared__ int      win[4][2][KNB];

    const int b0 = batch[i0];
    const int b1 = batch[i1];
    const int start0 = ranges[2 * b0], end0 = ranges[2 * b0 + 1];
    int start1 = start0, end1 = end0;
    if (b1 != b0) { start1 = ranges[2 * b1]; end1 = ranges[2 * b1 + 1]; }

    const float x0 = pos[3 * i0], y0 = pos[3 * i0 + 1], z0 = pos[3 * i0 + 2];
    const float x1 = pos[3 * i1], y1 = pos[3 * i1 + 1], z1 = pos[3 * i1 + 2];
    const float sq0 = x0 * x0 + y0 * y0 + z0 * z0;
    const float sq1 = x1 * x1 + y1 * y1 + z1 * z1;

    uint64_t (* const l0)[CAP] = &list[wave][0];
    uint64_t (* const l1)[CAP] = &list[wave][1];

    int cnt0 = 0, cnt1 = 0;
    if (b1 == b0) {
        // fused pass: one pos[j]/sqj load serves both atoms of the pair
        for (int jb = start0; jb < end0; jb += 64) {
            const int j = jb + lane;
            bool va = false, vb = false; uint64_t ka = 0, kb = 0;
            if (j < end0) {
                const float xj = pos[3 * j], yj = pos[3 * j + 1], zj = pos[3 * j + 2];
                const float sqj = xj * xj + yj * yj + zj * zj;
                if (j != i0) {
                    const float dot = x0 * xj + y0 * yj + z0 * zj;
                    const float d2  = (sq0 + sqj) - 2.0f * dot;       // reference's gram trick
                    const float dist = sqrtf(fmaxf(d2, 0.0f));
                    if (dist <= CUTOFF_F) { va = true; ka = ((uint64_t)__float_as_uint(dist) << 32) | (uint32_t)j; }
                }
                if (j != i1) {
                    const float dot = x1 * xj + y1 * yj + z1 * zj;
                    const float d2  = (sq1 + sqj) - 2.0f * dot;
                    const float dist = sqrtf(fmaxf(d2, 0.0f));
                    if (dist <= CUTOFF_F) { vb = true; kb = ((uint64_t)__float_as_uint(dist) << 32) | (uint32_t)j; }
                }
            }
            const unsigned long long m0 = __ballot(va);
            if (va) (*l0)[cnt0 + __popcll(m0 & ((1ULL << lane) - 1ULL))] = ka;
            cnt0 += __popcll(m0);
            const unsigned long long m1 = __ballot(vb);
            if (vb) (*l1)[cnt1 + __popcll(m1 & ((1ULL << lane) - 1ULL))] = kb;
            cnt1 += __popcll(m1);
        }
    } else {
        // rare split pair: two independent passes
        for (int jb = start0; jb < end0; jb += 64) {
            const int j = jb + lane;
            bool v = false; uint64_t k = 0;
            if (j < end0 && j != i0) {
                const float xj = pos[3 * j], yj = pos[3 * j + 1], zj = pos[3 * j + 2];
                const float sqj = xj * xj + yj * yj + zj * zj;
                const float dot = x0 * xj + y0 * yj + z0 * zj;
                const float d2  = (sq0 + sqj) - 2.0f * dot;
                const float dist = sqrtf(fmaxf(d2, 0.0f));
                if (dist <= CUTOFF_F) { v = true; k = ((uint64_t)__float_as_uint(dist) << 32) | (uint32_t)j; }
            }
            const unsigned long long m = __ballot(v);
            if (v) (*l0)[cnt0 + __popcll(m & ((1ULL << lane) - 1ULL))] = k;
            cnt0 += __popcll(m);
        }
        for (int jb = start1; jb < end1; jb += 64) {
            const int j = jb + lane;
            bool v = false; uint64_t k = 0;
            if (j < end1 && j != i1) {
                const float xj = pos[3 * j], yj = pos[3 * j + 1], zj = pos[3 * j + 2];
                const float sqj = xj * xj + yj * yj + zj * zj;
                const float dot = x1 * xj + y1 * yj + z1 * zj;
                const float d2  = (sq1 + sqj) - 2.0f * dot;
                const float dist = sqrtf(fmaxf(d2, 0.0f));
                if (dist <= CUTOFF_F) { v = true; k = ((uint64_t)__float_as_uint(dist) << 32) | (uint32_t)j; }
            }
            const unsigned long long m = __ballot(v);
            if (v) (*l1)[cnt1 + __popcll(m & ((1ULL << lane) - 1ULL))] = k;
            cnt1 += __popcll(m);
        }
    }

    if (lane < KNB) { win[wave][0][lane] = i0; win[wave][1][lane] = i1; }  // pads: self
    __syncthreads();

    const int C0 = cnt0, C1 = cnt1;
    for (int t = lane; t < C0; t += 64) {
        const uint64_t my = (*l0)[t]; int r = 0;
        #pragma unroll 4
        for (int u = 0; u < C0; ++u) r += ((*l0)[u] < my) ? 1 : 0;   // broadcast reads
        if (r < KNB) win[wave][0][r] = (int)(uint32_t)(my & 0xFFFFFFFFu);
    }
    for (int t = lane; t < C1; t += 64) {
        const uint64_t my = (*l1)[t]; int r = 0;
        #pragma unroll 4
        for (int u = 0; u < C1; ++u) r += ((*l1)[u] < my) ? 1 : 0;
        if (r < KNB) win[wave][1][r] = (int)(uint32_t)(my & 0xFFFFFFFFu);
    }
    __syncthreads();

    // epilogue: 64 lanes -> 64 contiguous edges (i0*KNB .. i0*KNB+63)
    const int half = lane >> 5;
    const int slot = lane & 31;
    const int a    = i0 + half;
    const int dst  = win[wave][half][slot];
    const int C    = half ? C1 : C0;
    const float ax = half ? x1 : x0, ay = half ? y1 : y0, az = half ? z1 : z0;
    const long long NK = (long long)N_ATOMS * KNB;
    const long long e  = (long long)a * KNB + slot;
    out[e]      = (float)a;
    out[NK + e] = (float)dst;
    // real edge: pos[dst]-pos[a]; pad: dst==a -> exactly 0.0
    out[2 * NK + 3 * e]     = pos[3 * dst]     - ax;
    out[2 * NK + 3 * e + 1] = pos[3 * dst + 1] - ay;
    out[2 * NK + 3 * e + 2] = pos[3 * dst + 2] - az;
    out[5 * NK + e] = (slot < C) ? 1.0f : 0.0f;
}

extern "C" void kernel_launch(void* const* d_in, const int* in_sizes, int n_in,
                              void* d_out, int out_size, void* d_ws, size_t ws_size,
                              hipStream_t stream) {
    const float* pos    = (const float*)d_in[0];   // [8192, 3] f32
    const int*   batch  = (const int*)d_in[1];     // [8192] i32, sorted
    float*       out    = (float*)d_out;           // 6*N*K floats
    int*         ranges = (int*)d_ws;              // [2*N_MOLS] ints

    mol_ranges_kernel<<<(N_ATOMS + 255) / 256, 256, 0, stream>>>(batch, ranges);
    radius_graph_kernel<<<N_ATOMS / 8, 256, 0, stream>>>(pos, batch, ranges, out);
}

// Round 6
// 65.684 us; speedup vs baseline: 1.0487x; 1.0487x over previous
//
#include <hip/hip_runtime.h>
#include <stdint.h>

#define N_ATOMS 8192
#define KNB 32            // MAX_NEIGHBORS
#define CUTOFF_F 5.0f
#define N_MOLS 64
#define CAP 256           // max supported molecule size (validated R1-R5)

// R6 = R3 verbatim (best measured: 65.4 us). R4 (pair-fusion, -50% loads) and
// R5 (fewer packets, precomputed ranges) were both neutral-to-worse -> the
// measured time is dominated by harness-fixed work (40.5 us d_ws poison fill
// at 82% HBM peak + ~20 us replay/restore overhead); kernel intrinsic cost is
// ~3-6 us and no longer movable.

// Kernel 1: molecule ranges via boundary detection on the sorted batch array.
__global__ void mol_ranges_kernel(const int* __restrict__ batch, int* __restrict__ ranges) {
    const int k = blockIdx.x * blockDim.x + threadIdx.x;
    if (k >= N_ATOMS) return;
    const int v = batch[k];
    if (k == 0) {
        ranges[2 * v] = 0;
    } else {
        const int w = batch[k - 1];
        if (w != v) { ranges[2 * w + 1] = k; ranges[2 * v] = k; }
    }
    if (k == N_ATOMS - 1) ranges[2 * v + 1] = N_ATOMS;
}

// Kernel 2: one 64-thread wave per atom. Valid keys (dist_bits<<32 | j) are
// wave-compacted into LDS; rank (#{strictly smaller}) is the output slot —
// exact jax.lax.top_k order (ascending dist, lower index first on ties).
__global__ __launch_bounds__(64) void radius_graph_kernel(
    const float* __restrict__ pos, const int* __restrict__ batch,
    const int* __restrict__ ranges, float* __restrict__ out)
{
    const int i    = blockIdx.x;
    const int lane = threadIdx.x;
    __shared__ uint64_t list[CAP];
    __shared__ int win[KNB];

    const int b     = batch[i];        // uniform -> scalar loads
    const int start = ranges[2 * b];
    const int end   = ranges[2 * b + 1];

    const float xi = pos[3 * i], yi = pos[3 * i + 1], zi = pos[3 * i + 2];
    const float sqi = xi * xi + yi * yi + zi * zi;

    int cnt = 0;                       // wave-uniform valid count
    #pragma unroll
    for (int q = 0; q < 4; ++q) {
        const int jbase = start + (q << 6);
        if (jbase >= end) break;       // uniform exit: most molecules need q<2
        const int j = jbase + lane;
        bool valid = false; uint64_t key = 0;
        if (j < end && j != i) {
            const float xj = pos[3 * j], yj = pos[3 * j + 1], zj = pos[3 * j + 2];
            const float sqj = xj * xj + yj * yj + zj * zj;
            const float dot = xi * xj + yi * yj + zi * zj;
            const float d2  = (sqi + sqj) - 2.0f * dot;     // reference's gram trick
            const float dist = sqrtf(fmaxf(d2, 0.0f));
            if (dist <= CUTOFF_F) {
                valid = true;
                key = ((uint64_t)__float_as_uint(dist) << 32) | (uint32_t)j;
            }
        }
        const unsigned long long m = __ballot(valid);
        if (valid)
            list[cnt + __popcll(m & ((1ULL << lane) - 1ULL))] = key;
        cnt += __popcll(m);
    }

    if (lane < KNB) win[lane] = i;     // default pad: self-edge
    __syncthreads();

    const int C = cnt;
    for (int t = lane; t < C; t += 64) {
        const uint64_t my = list[t];
        int r = 0;
        #pragma unroll 4
        for (int u = 0; u < C; ++u) r += (list[u] < my) ? 1 : 0;   // broadcast reads
        if (r < KNB) win[r] = (int)(uint32_t)(my & 0xFFFFFFFFu);
    }
    __syncthreads();

    if (lane < KNB) {
        const int dst = win[lane];
        const long long NK = (long long)N_ATOMS * KNB;
        const long long e  = (long long)i * KNB + lane;
        out[e]      = (float)i;
        out[NK + e] = (float)dst;
        // real edge: pos[dst]-pos[i]; pad: dst==i -> exactly 0.0
        out[2 * NK + 3 * e]     = pos[3 * dst]     - xi;
        out[2 * NK + 3 * e + 1] = pos[3 * dst + 1] - yi;
        out[2 * NK + 3 * e + 2] = pos[3 * dst + 2] - zi;
        out[5 * NK + e] = (lane < C) ? 1.0f : 0.0f;
    }
}

extern "C" void kernel_launch(void* const* d_in, const int* in_sizes, int n_in,
                              void* d_out, int out_size, void* d_ws, size_t ws_size,
                              hipStream_t stream) {
    const float* pos    = (const float*)d_in[0];   // [8192, 3] f32
    const int*   batch  = (const int*)d_in[1];     // [8192] i32, sorted
    float*       out    = (float*)d_out;           // 6*N*K floats
    int*         ranges = (int*)d_ws;              // [2*N_MOLS] ints

    mol_ranges_kernel<<<(N_ATOMS + 255) / 256, 256, 0, stream>>>(batch, ranges);
    radius_graph_kernel<<<N_ATOMS, 64, 0, stream>>>(pos, batch, ranges, out);
}